// Round 5
// baseline (862.144 us; speedup 1.0000x reference)
//
#include <hip/hip_runtime.h>
#include <hip/hip_bf16.h>
#include <hip/hip_cooperative_groups.h>

namespace cg = cooperative_groups;

#define FA_EPS 0.1f

typedef _Float16 half8  __attribute__((ext_vector_type(8)));
typedef _Float16 half2v __attribute__((ext_vector_type(2)));
typedef float    f32x4  __attribute__((ext_vector_type(4)));

// ---------------------------------------------------------------------------
// Mega cooperative kernel: all phases up to h16, separated by grid.sync().
//   A: al/ar dots, x->x16 copy, edeg=0; W -> Wt(f16,[n][k])
//   B: edge in-degree histogram
//   C: per-256-chunk exclusive scan (local) + chunk totals
//   D: block 0 scans chunk totals
//   E: finalize offs/cursor, dinv=rsqrt(deg+1)
//   F: counting-sort fill csr = {src, alpha}
//   G: gather from x16 -> h16 (fp32 accum), folds self-loop + EPS
// Grid: 1024 blocks x 256 (4 blocks/CU co-resident; VGPR<=128 via bounds).
// ---------------------------------------------------------------------------
__global__ __launch_bounds__(256, 4) void k_mega(
    const float* __restrict__ x, const int* __restrict__ ei,
    const float* __restrict__ att_l, const float* __restrict__ att_r,
    const float* __restrict__ w,
    float* __restrict__ al, float* __restrict__ ar, float* __restrict__ dinv,
    unsigned int* __restrict__ edeg, unsigned int* __restrict__ offs,
    unsigned int* __restrict__ cursor,
    unsigned int* __restrict__ partials, unsigned int* __restrict__ partial_offs,
    int2* __restrict__ csr, _Float16* __restrict__ x16,
    _Float16* __restrict__ h16, _Float16* __restrict__ wt,
    int N, int E, int NCH)
{
    cg::grid_group grid = cg::this_grid();
    __shared__ unsigned int s[256];
    const int tid      = threadIdx.x;
    const int gtid     = (int)blockIdx.x * 256 + tid;
    const int nthreads = (int)gridDim.x * 256;
    const int gwave    = gtid >> 6;
    const int nwaves   = nthreads >> 6;
    const int lane     = tid & 63;

    // ---- phase A: node prep + x16 + Wt ------------------------------------
    for (int node = gwave; node < N; node += nwaves) {
        const float2* xr = (const float2*)(x + (size_t)node * 128);
        float2 v  = xr[lane];
        float2 l2 = ((const float2*)att_l)[lane];
        float2 r2 = ((const float2*)att_r)[lane];
        half2v hv; hv[0] = (_Float16)v.x; hv[1] = (_Float16)v.y;
        *((half2v*)(x16 + (size_t)node * 128) + lane) = hv;
        float pal = v.x * l2.x + v.y * l2.y;
        float par = v.x * r2.x + v.y * r2.y;
        #pragma unroll
        for (int off = 32; off > 0; off >>= 1) {
            pal += __shfl_down(pal, off);
            par += __shfl_down(par, off);
        }
        if (lane == 0) {
            al[node] = pal;
            ar[node] = par;
            edeg[node] = 0u;
        }
    }
    for (int i = gtid; i < 128 * 128; i += nthreads) {
        int k = i >> 7, n = i & 127;
        wt[n * 128 + k] = (_Float16)w[k * 128 + n];
    }
    grid.sync();

    // ---- phase B: degree histogram ----------------------------------------
    for (int e = gtid; e < E; e += nthreads)
        atomicAdd(&edeg[ei[E + e]], 1u);
    grid.sync();

    // ---- phase C: per-chunk scan (chunk c -> block c) ---------------------
    for (int c = (int)blockIdx.x; c < NCH; c += (int)gridDim.x) {
        int i = c * 256 + tid;
        unsigned int v = (i < N) ? edeg[i] : 0u;
        s[tid] = v;
        __syncthreads();
        #pragma unroll
        for (int off = 1; off < 256; off <<= 1) {
            unsigned int t = (tid >= off) ? s[tid - off] : 0u;
            __syncthreads();
            s[tid] += t;
            __syncthreads();
        }
        if (i < N) offs[i] = s[tid] - v;       // local exclusive (no base yet)
        if (tid == 255) partials[c] = s[255];  // chunk total
        __syncthreads();
    }
    grid.sync();

    // ---- phase D: scan chunk totals (block 0; NCH <= 256) -----------------
    if (blockIdx.x == 0) {
        unsigned int v = (tid < NCH) ? partials[tid] : 0u;
        s[tid] = v;
        __syncthreads();
        #pragma unroll
        for (int off = 1; off < 256; off <<= 1) {
            unsigned int t = (tid >= off) ? s[tid - off] : 0u;
            __syncthreads();
            s[tid] += t;
            __syncthreads();
        }
        partial_offs[tid] = s[tid] - v;
    }
    grid.sync();

    // ---- phase E: finalize offs/cursor/dinv -------------------------------
    for (int i = gtid; i < N; i += nthreads) {
        unsigned int o = offs[i] + partial_offs[i >> 8];
        offs[i] = o;
        cursor[i] = o;
        dinv[i] = rsqrtf((float)(edeg[i] + 1u));   // +1: self-loop
    }
    grid.sync();

    // ---- phase F: counting-sort fill --------------------------------------
    for (int e = gtid; e < E; e += nthreads) {
        int sn = ei[e];
        int t  = ei[E + e];
        float alpha = tanhf(al[sn] + ar[t]) * dinv[sn] * dinv[t];
        unsigned int pos = atomicAdd(&cursor[t], 1u);
        csr[pos] = make_int2(sn, __float_as_int(alpha));
    }
    grid.sync();

    // ---- phase G: gather from x16 -> h16 ----------------------------------
    for (int t = gwave; t < N; t += nwaves) {
        const int2* cs = csr + offs[t];
        unsigned int cnt = edeg[t];
        float acc0 = 0.f, acc1 = 0.f;
        unsigned int j = 0;
        for (; j + 4 <= cnt; j += 4) {
            int2 e0 = cs[j + 0];
            int2 e1 = cs[j + 1];
            int2 e2 = cs[j + 2];
            int2 e3 = cs[j + 3];
            half2v v0 = *((const half2v*)(x16 + (size_t)e0.x * 128) + lane);
            half2v v1 = *((const half2v*)(x16 + (size_t)e1.x * 128) + lane);
            half2v v2 = *((const half2v*)(x16 + (size_t)e2.x * 128) + lane);
            half2v v3 = *((const half2v*)(x16 + (size_t)e3.x * 128) + lane);
            float a0 = __int_as_float(e0.y), a1 = __int_as_float(e1.y);
            float a2 = __int_as_float(e2.y), a3 = __int_as_float(e3.y);
            acc0 += a0 * (float)v0[0] + a1 * (float)v1[0] + a2 * (float)v2[0] + a3 * (float)v3[0];
            acc1 += a0 * (float)v0[1] + a1 * (float)v1[1] + a2 * (float)v2[1] + a3 * (float)v3[1];
        }
        for (; j < cnt; ++j) {
            int2 e = cs[j];
            half2v v = *((const half2v*)(x16 + (size_t)e.x * 128) + lane);
            float a = __int_as_float(e.y);
            acc0 += a * (float)v[0];
            acc1 += a * (float)v[1];
        }
        float di = dinv[t];
        float coef = tanhf(al[t] + ar[t]) * di * di + FA_EPS;   // self-loop + EPS
        half2v vt = *((const half2v*)(x16 + (size_t)t * 128) + lane);
        acc0 += coef * (float)vt[0];
        acc1 += coef * (float)vt[1];
        half2v hv; hv[0] = (_Float16)acc0; hv[1] = (_Float16)acc1;
        *((half2v*)(h16 + (size_t)t * 128) + lane) = hv;
    }
}

// ---------------------------------------------------------------------------
// Matmul: out = h16 @ W + bias via mfma_f32_16x16x32_f16 (same as round 4).
// Block = 4 waves, 64 rows. Wt in LDS, row stride 136 halfs (2-way = free).
// ---------------------------------------------------------------------------
__global__ __launch_bounds__(256) void k_matmul_mfma(
    const _Float16* __restrict__ h16,
    const _Float16* __restrict__ wt,
    const float* __restrict__ bias,
    float* __restrict__ out, int N)
{
    __shared__ _Float16 wl[128 * 136];   // 34 KB
    int tid = threadIdx.x;
    {
        const float* wsrc = (const float*)wt;
        float* wdst = (float*)wl;
        #pragma unroll
        for (int i = tid; i < 8192; i += 256)
            wdst[(i >> 6) * 68 + (i & 63)] = wsrc[i];
    }
    __syncthreads();
    int wv   = tid >> 6;
    int lane = tid & 63;
    int m    = lane & 15;
    int quad = lane >> 4;
    int r0 = (int)blockIdx.x * 64 + wv * 16;
    f32x4 acc[8];
    #pragma unroll
    for (int t = 0; t < 8; ++t) acc[t] = (f32x4)0.f;
    const _Float16* arow = h16 + (size_t)(r0 + m) * 128 + quad * 8;
    #pragma unroll
    for (int k0 = 0; k0 < 128; k0 += 32) {
        half8 a = *(const half8*)(arow + k0);
        #pragma unroll
        for (int t = 0; t < 8; ++t) {
            const _Float16* bp = wl + (size_t)(t * 16 + m) * 136 + quad * 8 + k0;
            half8 b = *(const half8*)bp;
            acc[t] = __builtin_amdgcn_mfma_f32_16x16x32_f16(a, b, acc[t], 0, 0, 0);
        }
    }
    int orow = r0 + quad * 4;
    #pragma unroll
    for (int t = 0; t < 8; ++t) {
        int col = t * 16 + m;
        float bc = bias[col];
        #pragma unroll
        for (int rg = 0; rg < 4; ++rg) {
            int r = orow + rg;
            if (r < N) out[(size_t)r * 128 + col] = acc[t][rg] + bc;
        }
    }
}

extern "C" void kernel_launch(void* const* d_in, const int* in_sizes, int n_in,
                              void* d_out, int out_size, void* d_ws, size_t ws_size,
                              hipStream_t stream)
{
    const float* x     = (const float*)d_in[0];
    const int*   ei    = (const int*)d_in[1];
    const float* att_l = (const float*)d_in[2];
    const float* att_r = (const float*)d_in[3];
    const float* w     = (const float*)d_in[4];
    const float* bias  = (const float*)d_in[5];
    float* out = (float*)d_out;

    const int N   = in_sizes[0] / 128;     // 50000
    const int E   = in_sizes[1] / 2;       // 600000
    const int NCH = (N + 255) / 256;       // 196 (<= 256)
    const int NP  = ((N + 63) / 64) * 64;  // 50048 rows (pad for MFMA tiles)

    char* ws = (char*)d_ws;
    _Float16*     h16          = (_Float16*)ws;                         // NP*128
    _Float16*     x16          = h16 + (size_t)NP * 128;                // N*128
    float*        al           = (float*)(x16 + (size_t)N * 128);       // N
    float*        ar           = al + N;
    float*        dinv         = ar + N;
    unsigned int* edeg         = (unsigned int*)(dinv + N);
    unsigned int* offs         = edeg + N;
    unsigned int* cursor       = offs + N;
    unsigned int* partials     = cursor + N;                            // 256
    unsigned int* partial_offs = partials + 256;                        // 256
    int2*         csr          = (int2*)(partial_offs + 256);           // E
    _Float16*     wt           = (_Float16*)(csr + E);                  // 16384

    int  Nv = N, Ev = E, NCHv = NCH;
    void* args[] = {
        (void*)&x, (void*)&ei, (void*)&att_l, (void*)&att_r, (void*)&w,
        (void*)&al, (void*)&ar, (void*)&dinv,
        (void*)&edeg, (void*)&offs, (void*)&cursor,
        (void*)&partials, (void*)&partial_offs,
        (void*)&csr, (void*)&x16, (void*)&h16, (void*)&wt,
        (void*)&Nv, (void*)&Ev, (void*)&NCHv,
    };
    hipLaunchCooperativeKernel((const void*)k_mega, dim3(1024), dim3(256),
                               args, 0, stream);

    k_matmul_mfma<<<NP / 64, 256, 0, stream>>>(h16, wt, bias, out, N);
}

// Round 6
// 329.932 us; speedup vs baseline: 2.6131x; 2.6131x over previous
//
#include <hip/hip_runtime.h>
#include <hip/hip_bf16.h>

#define FA_EPS 0.1f

typedef _Float16 half8  __attribute__((ext_vector_type(8)));
typedef _Float16 half2v __attribute__((ext_vector_type(2)));
typedef float    f32x4  __attribute__((ext_vector_type(4)));

// ---------------------------------------------------------------------------
// K0: per-node prep. One wave per node:
//   al/ar dots; x -> x16 (f16); edeg = 0
// ---------------------------------------------------------------------------
__global__ __launch_bounds__(256) void k_node_prep(
    const float* __restrict__ x,
    const float* __restrict__ att_l,
    const float* __restrict__ att_r,
    float* __restrict__ al, float* __restrict__ ar,
    unsigned int* __restrict__ edeg, _Float16* __restrict__ x16, int N)
{
    int node = (int)((blockIdx.x * blockDim.x + threadIdx.x) >> 6);
    int lane = threadIdx.x & 63;
    if (node >= N) return;
    const float2* xr = (const float2*)(x + (size_t)node * 128);
    float2 v  = xr[lane];
    float2 l2 = ((const float2*)att_l)[lane];
    float2 r2 = ((const float2*)att_r)[lane];
    half2v hv; hv[0] = (_Float16)v.x; hv[1] = (_Float16)v.y;
    *((half2v*)(x16 + (size_t)node * 128) + lane) = hv;
    float pal = v.x * l2.x + v.y * l2.y;
    float par = v.x * r2.x + v.y * r2.y;
    #pragma unroll
    for (int off = 32; off > 0; off >>= 1) {
        pal += __shfl_down(pal, off);
        par += __shfl_down(par, off);
    }
    if (lane == 0) {
        al[node] = pal;
        ar[node] = par;
        edeg[node] = 0u;
    }
}

// ---------------------------------------------------------------------------
// K1: edge in-degree histogram; first 64 blocks also build Wt (f16 [n][k]).
// ---------------------------------------------------------------------------
__global__ __launch_bounds__(256) void k_degree_wconv(
    const int* __restrict__ ei, unsigned int* __restrict__ edeg,
    const float* __restrict__ w, _Float16* __restrict__ wt, int E)
{
    int g = (int)(blockIdx.x * blockDim.x + threadIdx.x);
    if (g < 128 * 128) {
        int k = g >> 7, n = g & 127;
        wt[n * 128 + k] = (_Float16)w[k * 128 + n];
    }
    if (g < E) atomicAdd(&edeg[ei[E + g]], 1u);
}

// ---------------------------------------------------------------------------
// K2: single-block scan. 1024 threads; thread t owns a contiguous chunk of
// CH = ceil(N/1024) nodes: local sum -> block exclusive scan -> write
// offs/cursor (exclusive prefix) and dinv = rsqrt(edeg+1).
// ---------------------------------------------------------------------------
__global__ __launch_bounds__(1024) void k_scan_all(
    const unsigned int* __restrict__ edeg,
    unsigned int* __restrict__ offs, unsigned int* __restrict__ cursor,
    float* __restrict__ dinv, int N, int CH)
{
    __shared__ unsigned int s[1024];
    int tid = threadIdx.x;
    int beg = tid * CH;
    int end = min(beg + CH, N);
    unsigned int sum = 0;
    for (int i = beg; i < end; ++i) sum += edeg[i];
    s[tid] = sum;
    __syncthreads();
    #pragma unroll
    for (int off = 1; off < 1024; off <<= 1) {
        unsigned int t = (tid >= off) ? s[tid - off] : 0u;
        __syncthreads();
        s[tid] += t;
        __syncthreads();
    }
    unsigned int run = s[tid] - sum;   // exclusive base for this chunk
    for (int i = beg; i < end; ++i) {
        unsigned int d = edeg[i];
        offs[i] = run;
        cursor[i] = run;
        dinv[i] = rsqrtf((float)(d + 1u));   // +1: self-loop
        run += d;
    }
}

// ---------------------------------------------------------------------------
// K3: bucket fill — counting sort of edges by target; csr = {src, alpha}
// ---------------------------------------------------------------------------
__global__ __launch_bounds__(256) void k_fill(
    const int* __restrict__ ei,
    const float* __restrict__ al, const float* __restrict__ ar,
    const float* __restrict__ dinv,
    unsigned int* __restrict__ cursor,
    int2* __restrict__ csr, int E)
{
    int e = (int)(blockIdx.x * blockDim.x + threadIdx.x);
    if (e >= E) return;
    int s = ei[e];
    int t = ei[E + e];
    float alpha = tanhf(al[s] + ar[t]) * dinv[s] * dinv[t];
    unsigned int pos = atomicAdd(&cursor[t], 1u);
    csr[pos] = make_int2(s, __float_as_int(alpha));
}

// ---------------------------------------------------------------------------
// K4: gather — one wave per target; x16 rows (256 B), predicated unroll-8
// chunks so 8 row-loads are always in flight (no serial remainder loop).
//   h16[t,:] = (f16)[ sum_in alpha*x16[s,:] + (tanh(al+ar)*dinv^2+EPS)*x16[t,:] ]
// ---------------------------------------------------------------------------
__global__ __launch_bounds__(256) void k_gather(
    const _Float16* __restrict__ x16,
    const int2* __restrict__ csr,
    const unsigned int* __restrict__ offs, const unsigned int* __restrict__ edeg,
    const float* __restrict__ al, const float* __restrict__ ar,
    const float* __restrict__ dinv, _Float16* __restrict__ h16, int N)
{
    int t = (int)((blockIdx.x * blockDim.x + threadIdx.x) >> 6);
    int lane = threadIdx.x & 63;
    if (t >= N) return;
    const int2* cs = csr + offs[t];
    unsigned int cnt = edeg[t];
    float acc0 = 0.f, acc1 = 0.f;
    for (unsigned int j = 0; j < cnt; j += 8) {
        int2 e[8];
        #pragma unroll
        for (int u = 0; u < 8; ++u) {
            unsigned int idx = (j + u < cnt) ? (j + u) : (cnt - 1);
            e[u] = cs[idx];
        }
        #pragma unroll
        for (int u = 0; u < 8; ++u)
            if (j + u >= cnt) e[u].y = 0;          // alpha := 0.0f for pad slots
        half2v v[8];
        #pragma unroll
        for (int u = 0; u < 8; ++u)
            v[u] = *((const half2v*)(x16 + (size_t)e[u].x * 128) + lane);
        #pragma unroll
        for (int u = 0; u < 8; ++u) {
            float a = __int_as_float(e[u].y);
            acc0 += a * (float)v[u][0];
            acc1 += a * (float)v[u][1];
        }
    }
    float di = dinv[t];
    float coef = tanhf(al[t] + ar[t]) * di * di + FA_EPS;   // self-loop + EPS
    half2v vt = *((const half2v*)(x16 + (size_t)t * 128) + lane);
    acc0 += coef * (float)vt[0];
    acc1 += coef * (float)vt[1];
    half2v hv; hv[0] = (_Float16)acc0; hv[1] = (_Float16)acc1;
    *((half2v*)(h16 + (size_t)t * 128) + lane) = hv;
}

// ---------------------------------------------------------------------------
// K5: out = h16 @ W + bias via mfma_f32_16x16x32_f16.
// Block = 4 waves, 64 rows. Wt in LDS, row stride 136 halfs (2-way = free).
// A-frag: lane holds h16[r0+(lane&15)][quad*8 + k0 ..+7]; D: col=lane&15,
// row=quad*4+reg.
// ---------------------------------------------------------------------------
__global__ __launch_bounds__(256) void k_matmul_mfma(
    const _Float16* __restrict__ h16,
    const _Float16* __restrict__ wt,
    const float* __restrict__ bias,
    float* __restrict__ out, int N)
{
    __shared__ _Float16 wl[128 * 136];   // 34 KB
    int tid = threadIdx.x;
    {
        const float* wsrc = (const float*)wt;
        float* wdst = (float*)wl;
        #pragma unroll
        for (int i = tid; i < 8192; i += 256)
            wdst[(i >> 6) * 68 + (i & 63)] = wsrc[i];
    }
    __syncthreads();
    int wv   = tid >> 6;
    int lane = tid & 63;
    int m    = lane & 15;
    int quad = lane >> 4;
    int r0 = (int)blockIdx.x * 64 + wv * 16;
    f32x4 acc[8];
    #pragma unroll
    for (int t = 0; t < 8; ++t) acc[t] = (f32x4)0.f;
    const _Float16* arow = h16 + (size_t)(r0 + m) * 128 + quad * 8;
    #pragma unroll
    for (int k0 = 0; k0 < 128; k0 += 32) {
        half8 a = *(const half8*)(arow + k0);
        #pragma unroll
        for (int t = 0; t < 8; ++t) {
            const _Float16* bp = wl + (size_t)(t * 16 + m) * 136 + quad * 8 + k0;
            half8 b = *(const half8*)bp;
            acc[t] = __builtin_amdgcn_mfma_f32_16x16x32_f16(a, b, acc[t], 0, 0, 0);
        }
    }
    int orow = r0 + quad * 4;
    #pragma unroll
    for (int t = 0; t < 8; ++t) {
        int col = t * 16 + m;
        float bc = bias[col];
        #pragma unroll
        for (int rg = 0; rg < 4; ++rg) {
            int r = orow + rg;
            if (r < N) out[(size_t)r * 128 + col] = acc[t][rg] + bc;
        }
    }
}

extern "C" void kernel_launch(void* const* d_in, const int* in_sizes, int n_in,
                              void* d_out, int out_size, void* d_ws, size_t ws_size,
                              hipStream_t stream)
{
    const float* x     = (const float*)d_in[0];
    const int*   ei    = (const int*)d_in[1];
    const float* att_l = (const float*)d_in[2];
    const float* att_r = (const float*)d_in[3];
    const float* w     = (const float*)d_in[4];
    const float* bias  = (const float*)d_in[5];
    float* out = (float*)d_out;

    const int N  = in_sizes[0] / 128;     // 50000
    const int E  = in_sizes[1] / 2;       // 600000
    const int NP = ((N + 63) / 64) * 64;  // pad rows for 64-row MFMA tiles
    const int CH = (N + 1023) / 1024;     // scan chunk per thread

    char* ws = (char*)d_ws;
    _Float16*     h16    = (_Float16*)ws;                         // NP*128
    _Float16*     x16    = h16 + (size_t)NP * 128;                // N*128
    float*        al     = (float*)(x16 + (size_t)N * 128);       // N
    float*        ar     = al + N;
    float*        dinv   = ar + N;
    unsigned int* edeg   = (unsigned int*)(dinv + N);
    unsigned int* offs   = edeg + N;
    unsigned int* cursor = offs + N;
    int2*         csr    = (int2*)(cursor + N);                   // E
    _Float16*     wt     = (_Float16*)(csr + E);                  // 16384

    // K0: al/ar dots, x16 conversion, edeg=0
    k_node_prep<<<(N * 64 + 255) / 256, 256, 0, stream>>>(x, att_l, att_r, al, ar,
                                                          edeg, x16, N);
    // K1: degree histogram (+ Wt conversion in low blocks)
    k_degree_wconv<<<(E + 255) / 256, 256, 0, stream>>>(ei, edeg, w, wt, E);
    // K2: single-block scan -> offs/cursor/dinv
    k_scan_all<<<1, 1024, 0, stream>>>(edeg, offs, cursor, dinv, N, CH);
    // K3: counting-sort fill
    k_fill<<<(E + 255) / 256, 256, 0, stream>>>(ei, al, ar, dinv, cursor, csr, E);
    // K4: gather from x16
    k_gather<<<(N * 64 + 255) / 256, 256, 0, stream>>>(x16, csr, offs, edeg,
                                                       al, ar, dinv, h16, N);
    // K5: matmul + bias
    k_matmul_mfma<<<NP / 64, 256, 0, stream>>>(h16, wt, bias, out, N);
}

// Round 7
// 206.818 us; speedup vs baseline: 4.1686x; 1.5953x over previous
//
#include <hip/hip_runtime.h>
#include <hip/hip_bf16.h>

#define FA_EPS 0.1f

typedef _Float16 half8  __attribute__((ext_vector_type(8)));
typedef _Float16 half2v __attribute__((ext_vector_type(2)));
typedef float    f32x4  __attribute__((ext_vector_type(4)));

// ---------------------------------------------------------------------------
// K0: per-node prep. One wave per node:
//   al/ar dots; x -> x16 (f16); edeg = 0
// ---------------------------------------------------------------------------
__global__ __launch_bounds__(256) void k_node_prep(
    const float* __restrict__ x,
    const float* __restrict__ att_l,
    const float* __restrict__ att_r,
    float* __restrict__ al, float* __restrict__ ar,
    unsigned int* __restrict__ edeg, _Float16* __restrict__ x16, int N)
{
    int node = (int)((blockIdx.x * blockDim.x + threadIdx.x) >> 6);
    int lane = threadIdx.x & 63;
    if (node >= N) return;
    const float2* xr = (const float2*)(x + (size_t)node * 128);
    float2 v  = xr[lane];
    float2 l2 = ((const float2*)att_l)[lane];
    float2 r2 = ((const float2*)att_r)[lane];
    half2v hv; hv[0] = (_Float16)v.x; hv[1] = (_Float16)v.y;
    *((half2v*)(x16 + (size_t)node * 128) + lane) = hv;
    float pal = v.x * l2.x + v.y * l2.y;
    float par = v.x * r2.x + v.y * r2.y;
    #pragma unroll
    for (int off = 32; off > 0; off >>= 1) {
        pal += __shfl_down(pal, off);
        par += __shfl_down(par, off);
    }
    if (lane == 0) {
        al[node] = pal;
        ar[node] = par;
        edeg[node] = 0u;
    }
}

// ---------------------------------------------------------------------------
// K1: edge in-degree histogram; first 64 blocks also build Wt (f16 [n][k]).
// ---------------------------------------------------------------------------
__global__ __launch_bounds__(256) void k_degree_wconv(
    const int* __restrict__ ei, unsigned int* __restrict__ edeg,
    const float* __restrict__ w, _Float16* __restrict__ wt, int E)
{
    int g = (int)(blockIdx.x * blockDim.x + threadIdx.x);
    if (g < 128 * 128) {
        int k = g >> 7, n = g & 127;
        wt[n * 128 + k] = (_Float16)w[k * 128 + n];
    }
    if (g < E) atomicAdd(&edeg[ei[E + g]], 1u);
}

// ---------------------------------------------------------------------------
// K2: per-256-chunk reduction of edeg -> partials[b]
// ---------------------------------------------------------------------------
__global__ __launch_bounds__(256) void k_reduce(
    const unsigned int* __restrict__ edeg, unsigned int* __restrict__ partials,
    int N)
{
    __shared__ unsigned int lds[4];
    int i = (int)(blockIdx.x * blockDim.x + threadIdx.x);
    unsigned int v = (i < N) ? edeg[i] : 0u;
    #pragma unroll
    for (int off = 32; off > 0; off >>= 1) v += __shfl_down(v, off);
    int lane = threadIdx.x & 63, wid = threadIdx.x >> 6;
    if (lane == 0) lds[wid] = v;
    __syncthreads();
    if (threadIdx.x == 0)
        partials[blockIdx.x] = lds[0] + lds[1] + lds[2] + lds[3];
}

// ---------------------------------------------------------------------------
// K3: exclusive scan of partials (single block; NB <= 256 — tiny data)
// ---------------------------------------------------------------------------
__global__ __launch_bounds__(256) void k_scan_partials(
    const unsigned int* __restrict__ partials,
    unsigned int* __restrict__ partial_offs, int NB)
{
    __shared__ unsigned int s[256];
    int tid = threadIdx.x;
    unsigned int v = (tid < NB) ? partials[tid] : 0u;
    s[tid] = v;
    __syncthreads();
    #pragma unroll
    for (int off = 1; off < 256; off <<= 1) {
        unsigned int t = (tid >= off) ? s[tid - off] : 0u;
        __syncthreads();
        s[tid] += t;
        __syncthreads();
    }
    partial_offs[tid] = s[tid] - v;
}

// ---------------------------------------------------------------------------
// K4: per-chunk exclusive scan + base -> offs, cursor; dinv = rsqrt(edeg+1)
// ---------------------------------------------------------------------------
__global__ __launch_bounds__(256) void k_chunk_scan(
    const unsigned int* __restrict__ edeg,
    const unsigned int* __restrict__ partial_offs,
    unsigned int* __restrict__ offs, unsigned int* __restrict__ cursor,
    float* __restrict__ dinv, int N)
{
    __shared__ unsigned int s[256];
    int tid = threadIdx.x;
    int i = (int)(blockIdx.x * blockDim.x + tid);
    unsigned int v = (i < N) ? edeg[i] : 0u;
    s[tid] = v;
    __syncthreads();
    #pragma unroll
    for (int off = 1; off < 256; off <<= 1) {
        unsigned int t = (tid >= off) ? s[tid - off] : 0u;
        __syncthreads();
        s[tid] += t;
        __syncthreads();
    }
    if (i < N) {
        unsigned int o = partial_offs[blockIdx.x] + s[tid] - v;
        offs[i] = o;
        cursor[i] = o;
        dinv[i] = rsqrtf((float)(v + 1u));   // +1: self-loop
    }
}

// ---------------------------------------------------------------------------
// K5: bucket fill — counting sort of edges by target; csr = {src, alpha}
// ---------------------------------------------------------------------------
__global__ __launch_bounds__(256) void k_fill(
    const int* __restrict__ ei,
    const float* __restrict__ al, const float* __restrict__ ar,
    const float* __restrict__ dinv,
    unsigned int* __restrict__ cursor,
    int2* __restrict__ csr, int E)
{
    int e = (int)(blockIdx.x * blockDim.x + threadIdx.x);
    if (e >= E) return;
    int s = ei[e];
    int t = ei[E + e];
    float alpha = tanhf(al[s] + ar[t]) * dinv[s] * dinv[t];
    unsigned int pos = atomicAdd(&cursor[t], 1u);
    csr[pos] = make_int2(s, __float_as_int(alpha));
}

// ---------------------------------------------------------------------------
// K6: gather — one wave per target; x16 rows (256 B), predicated unroll-8
// chunks so 8 row-loads are always in flight (no serial remainder loop).
//   h16[t,:] = (f16)[ sum_in alpha*x16[s,:] + (tanh(al+ar)*dinv^2+EPS)*x16[t,:] ]
// ---------------------------------------------------------------------------
__global__ __launch_bounds__(256) void k_gather(
    const _Float16* __restrict__ x16,
    const int2* __restrict__ csr,
    const unsigned int* __restrict__ offs, const unsigned int* __restrict__ edeg,
    const float* __restrict__ al, const float* __restrict__ ar,
    const float* __restrict__ dinv, _Float16* __restrict__ h16, int N)
{
    int t = (int)((blockIdx.x * blockDim.x + threadIdx.x) >> 6);
    int lane = threadIdx.x & 63;
    if (t >= N) return;
    const int2* cs = csr + offs[t];
    unsigned int cnt = edeg[t];
    float acc0 = 0.f, acc1 = 0.f;
    for (unsigned int j = 0; j < cnt; j += 8) {
        int2 e[8];
        #pragma unroll
        for (int u = 0; u < 8; ++u) {
            unsigned int idx = (j + u < cnt) ? (j + u) : (cnt - 1);
            e[u] = cs[idx];
        }
        #pragma unroll
        for (int u = 0; u < 8; ++u)
            if (j + u >= cnt) e[u].y = 0;          // alpha := 0.0f for pad slots
        half2v v[8];
        #pragma unroll
        for (int u = 0; u < 8; ++u)
            v[u] = *((const half2v*)(x16 + (size_t)e[u].x * 128) + lane);
        #pragma unroll
        for (int u = 0; u < 8; ++u) {
            float a = __int_as_float(e[u].y);
            acc0 += a * (float)v[u][0];
            acc1 += a * (float)v[u][1];
        }
    }
    float di = dinv[t];
    float coef = tanhf(al[t] + ar[t]) * di * di + FA_EPS;   // self-loop + EPS
    half2v vt = *((const half2v*)(x16 + (size_t)t * 128) + lane);
    acc0 += coef * (float)vt[0];
    acc1 += coef * (float)vt[1];
    half2v hv; hv[0] = (_Float16)acc0; hv[1] = (_Float16)acc1;
    *((half2v*)(h16 + (size_t)t * 128) + lane) = hv;
}

// ---------------------------------------------------------------------------
// K7: out = h16 @ W + bias via mfma_f32_16x16x32_f16.
// Block = 4 waves, 64 rows. Wt in LDS, row stride 136 halfs (2-way = free).
// ---------------------------------------------------------------------------
__global__ __launch_bounds__(256) void k_matmul_mfma(
    const _Float16* __restrict__ h16,
    const _Float16* __restrict__ wt,
    const float* __restrict__ bias,
    float* __restrict__ out, int N)
{
    __shared__ _Float16 wl[128 * 136];   // 34 KB
    int tid = threadIdx.x;
    {
        const float* wsrc = (const float*)wt;
        float* wdst = (float*)wl;
        #pragma unroll
        for (int i = tid; i < 8192; i += 256)
            wdst[(i >> 6) * 68 + (i & 63)] = wsrc[i];
    }
    __syncthreads();
    int wv   = tid >> 6;
    int lane = tid & 63;
    int m    = lane & 15;
    int quad = lane >> 4;
    int r0 = (int)blockIdx.x * 64 + wv * 16;
    f32x4 acc[8];
    #pragma unroll
    for (int t = 0; t < 8; ++t) acc[t] = (f32x4)0.f;
    const _Float16* arow = h16 + (size_t)(r0 + m) * 128 + quad * 8;
    #pragma unroll
    for (int k0 = 0; k0 < 128; k0 += 32) {
        half8 a = *(const half8*)(arow + k0);
        #pragma unroll
        for (int t = 0; t < 8; ++t) {
            const _Float16* bp = wl + (size_t)(t * 16 + m) * 136 + quad * 8 + k0;
            half8 b = *(const half8*)bp;
            acc[t] = __builtin_amdgcn_mfma_f32_16x16x32_f16(a, b, acc[t], 0, 0, 0);
        }
    }
    int orow = r0 + quad * 4;
    #pragma unroll
    for (int t = 0; t < 8; ++t) {
        int col = t * 16 + m;
        float bc = bias[col];
        #pragma unroll
        for (int rg = 0; rg < 4; ++rg) {
            int r = orow + rg;
            if (r < N) out[(size_t)r * 128 + col] = acc[t][rg] + bc;
        }
    }
}

extern "C" void kernel_launch(void* const* d_in, const int* in_sizes, int n_in,
                              void* d_out, int out_size, void* d_ws, size_t ws_size,
                              hipStream_t stream)
{
    const float* x     = (const float*)d_in[0];
    const int*   ei    = (const int*)d_in[1];
    const float* att_l = (const float*)d_in[2];
    const float* att_r = (const float*)d_in[3];
    const float* w     = (const float*)d_in[4];
    const float* bias  = (const float*)d_in[5];
    float* out = (float*)d_out;

    const int N  = in_sizes[0] / 128;     // 50000
    const int E  = in_sizes[1] / 2;       // 600000
    const int NB = (N + 255) / 256;       // 196 (<= 256)
    const int NP = ((N + 63) / 64) * 64;  // pad rows for 64-row MFMA tiles

    char* ws = (char*)d_ws;
    _Float16*     h16          = (_Float16*)ws;                         // NP*128
    _Float16*     x16          = h16 + (size_t)NP * 128;                // N*128
    float*        al           = (float*)(x16 + (size_t)N * 128);       // N
    float*        ar           = al + N;
    float*        dinv         = ar + N;
    unsigned int* edeg         = (unsigned int*)(dinv + N);
    unsigned int* offs         = edeg + N;
    unsigned int* cursor       = offs + N;
    unsigned int* partials     = cursor + N;                            // 256
    unsigned int* partial_offs = partials + 256;                        // 256
    int2*         csr          = (int2*)(partial_offs + 256);           // E
    _Float16*     wt           = (_Float16*)(csr + E);                  // 16384

    // K0: al/ar dots, x16 conversion, edeg=0
    k_node_prep<<<(N * 64 + 255) / 256, 256, 0, stream>>>(x, att_l, att_r, al, ar,
                                                          edeg, x16, N);
    // K1: degree histogram (+ Wt conversion in low blocks)
    k_degree_wconv<<<(E + 255) / 256, 256, 0, stream>>>(ei, edeg, w, wt, E);
    // K2-K4: parallel two-level exclusive scan -> offs/cursor/dinv
    k_reduce<<<NB, 256, 0, stream>>>(edeg, partials, N);
    k_scan_partials<<<1, 256, 0, stream>>>(partials, partial_offs, NB);
    k_chunk_scan<<<NB, 256, 0, stream>>>(edeg, partial_offs, offs, cursor, dinv, N);
    // K5: counting-sort fill
    k_fill<<<(E + 255) / 256, 256, 0, stream>>>(ei, al, ar, dinv, cursor, csr, E);
    // K6: gather from x16
    k_gather<<<(N * 64 + 255) / 256, 256, 0, stream>>>(x16, csr, offs, edeg,
                                                       al, ar, dinv, h16, N);
    // K7: matmul + bias
    k_matmul_mfma<<<NP / 64, 256, 0, stream>>>(h16, wt, bias, out, N);
}

// Round 8
// 190.687 us; speedup vs baseline: 4.5213x; 1.0846x over previous
//
#include <hip/hip_runtime.h>
#include <hip/hip_bf16.h>

#define FA_EPS 0.1f

typedef _Float16 half8  __attribute__((ext_vector_type(8)));
typedef _Float16 half4v __attribute__((ext_vector_type(4)));
typedef float    f32x4  __attribute__((ext_vector_type(4)));

// ---------------------------------------------------------------------------
// K0: per-node prep, 2 nodes/wave (32 lanes x float4 = 512 B row):
//   al/ar dots (xor-shuffle within 32-lane half); x -> x16 (f16); edeg = 0
// ---------------------------------------------------------------------------
__global__ __launch_bounds__(256) void k_node_prep(
    const float* __restrict__ x,
    const float* __restrict__ att_l,
    const float* __restrict__ att_r,
    float* __restrict__ al, float* __restrict__ ar,
    unsigned int* __restrict__ edeg, _Float16* __restrict__ x16, int N)
{
    int wave = (int)((blockIdx.x * blockDim.x + threadIdx.x) >> 6);
    int lane = threadIdx.x & 63;
    int half = lane >> 5;          // 0/1: which node in this wave
    int sl   = lane & 31;          // sublane within 32
    int node = wave * 2 + half;
    if (node >= N) return;
    const float4* xr = (const float4*)(x + (size_t)node * 128);   // 32 x 16B
    float4 v  = xr[sl];
    float4 l4 = ((const float4*)att_l)[sl];
    float4 r4 = ((const float4*)att_r)[sl];
    half4v hv;
    hv[0] = (_Float16)v.x; hv[1] = (_Float16)v.y;
    hv[2] = (_Float16)v.z; hv[3] = (_Float16)v.w;
    *((half4v*)(x16 + (size_t)node * 128) + sl) = hv;
    float pal = v.x * l4.x + v.y * l4.y + v.z * l4.z + v.w * l4.w;
    float par = v.x * r4.x + v.y * r4.y + v.z * r4.z + v.w * r4.w;
    #pragma unroll
    for (int off = 16; off > 0; off >>= 1) {      // xor stays within 32-half
        pal += __shfl_xor(pal, off);
        par += __shfl_xor(par, off);
    }
    if (sl == 0) {
        al[node] = pal;
        ar[node] = par;
        edeg[node] = 0u;
    }
}

// ---------------------------------------------------------------------------
// K1: edge in-degree histogram; first 64 blocks also build Wt (f16 [n][k]).
// ---------------------------------------------------------------------------
__global__ __launch_bounds__(256) void k_degree_wconv(
    const int* __restrict__ ei, unsigned int* __restrict__ edeg,
    const float* __restrict__ w, _Float16* __restrict__ wt, int E)
{
    int g = (int)(blockIdx.x * blockDim.x + threadIdx.x);
    if (g < 128 * 128) {
        int k = g >> 7, n = g & 127;
        wt[n * 128 + k] = (_Float16)w[k * 128 + n];
    }
    if (g < E) atomicAdd(&edeg[ei[E + g]], 1u);
}

// ---------------------------------------------------------------------------
// K2: per-256-chunk reduction of edeg -> partials[b]
// ---------------------------------------------------------------------------
__global__ __launch_bounds__(256) void k_reduce(
    const unsigned int* __restrict__ edeg, unsigned int* __restrict__ partials,
    int N)
{
    __shared__ unsigned int lds[4];
    int i = (int)(blockIdx.x * blockDim.x + threadIdx.x);
    unsigned int v = (i < N) ? edeg[i] : 0u;
    #pragma unroll
    for (int off = 32; off > 0; off >>= 1) v += __shfl_down(v, off);
    int lane = threadIdx.x & 63, wid = threadIdx.x >> 6;
    if (lane == 0) lds[wid] = v;
    __syncthreads();
    if (threadIdx.x == 0)
        partials[blockIdx.x] = lds[0] + lds[1] + lds[2] + lds[3];
}

// ---------------------------------------------------------------------------
// K3: exclusive scan of partials (single block; NB <= 256 — tiny data)
// ---------------------------------------------------------------------------
__global__ __launch_bounds__(256) void k_scan_partials(
    const unsigned int* __restrict__ partials,
    unsigned int* __restrict__ partial_offs, int NB)
{
    __shared__ unsigned int s[256];
    int tid = threadIdx.x;
    unsigned int v = (tid < NB) ? partials[tid] : 0u;
    s[tid] = v;
    __syncthreads();
    #pragma unroll
    for (int off = 1; off < 256; off <<= 1) {
        unsigned int t = (tid >= off) ? s[tid - off] : 0u;
        __syncthreads();
        s[tid] += t;
        __syncthreads();
    }
    partial_offs[tid] = s[tid] - v;
}

// ---------------------------------------------------------------------------
// K4: per-chunk exclusive scan + base -> offs, cursor; dinv = rsqrt(edeg+1)
// ---------------------------------------------------------------------------
__global__ __launch_bounds__(256) void k_chunk_scan(
    const unsigned int* __restrict__ edeg,
    const unsigned int* __restrict__ partial_offs,
    unsigned int* __restrict__ offs, unsigned int* __restrict__ cursor,
    float* __restrict__ dinv, int N)
{
    __shared__ unsigned int s[256];
    int tid = threadIdx.x;
    int i = (int)(blockIdx.x * blockDim.x + tid);
    unsigned int v = (i < N) ? edeg[i] : 0u;
    s[tid] = v;
    __syncthreads();
    #pragma unroll
    for (int off = 1; off < 256; off <<= 1) {
        unsigned int t = (tid >= off) ? s[tid - off] : 0u;
        __syncthreads();
        s[tid] += t;
        __syncthreads();
    }
    if (i < N) {
        unsigned int o = partial_offs[blockIdx.x] + s[tid] - v;
        offs[i] = o;
        cursor[i] = o;
        dinv[i] = rsqrtf((float)(v + 1u));   // +1: self-loop
    }
}

// ---------------------------------------------------------------------------
// K5: bucket fill — counting sort of edges by target; csr = {src, alpha}
// ---------------------------------------------------------------------------
__global__ __launch_bounds__(256) void k_fill(
    const int* __restrict__ ei,
    const float* __restrict__ al, const float* __restrict__ ar,
    const float* __restrict__ dinv,
    unsigned int* __restrict__ cursor,
    int2* __restrict__ csr, int E)
{
    int e = (int)(blockIdx.x * blockDim.x + threadIdx.x);
    if (e >= E) return;
    int s = ei[e];
    int t = ei[E + e];
    float alpha = tanhf(al[s] + ar[t]) * dinv[s] * dinv[t];
    unsigned int pos = atomicAdd(&cursor[t], 1u);
    csr[pos] = make_int2(s, __float_as_int(alpha));
}

// ---------------------------------------------------------------------------
// K6: gather — 4 nodes per wave; 16 lanes x half8 (16 B) per 256 B row.
// One load instruction fetches 4 different edge-rows (one per quarter-wave):
// ~4x fewer VMEM instructions/edge vs wave-per-node at max-of-4 loop padding.
//   h16[t,:] = (f16)[ sum_in alpha*x16[s,:] + (tanh(al+ar)*dinv^2+EPS)*x16[t,:] ]
// ---------------------------------------------------------------------------
__global__ __launch_bounds__(256) void k_gather(
    const _Float16* __restrict__ x16,
    const int2* __restrict__ csr,
    const unsigned int* __restrict__ offs, const unsigned int* __restrict__ edeg,
    const float* __restrict__ al, const float* __restrict__ ar,
    const float* __restrict__ dinv, _Float16* __restrict__ h16, int N)
{
    int wave = (int)((blockIdx.x * blockDim.x + threadIdx.x) >> 6);
    int lane = threadIdx.x & 63;
    int g  = lane >> 4;            // quarter-wave group: which node
    int sl = lane & 15;            // sublane: which 8-col slice
    int t  = wave * 4 + g;
    bool valid = t < N;
    int tc = valid ? t : N - 1;    // clamped for loads
    const int2* cs = csr + offs[tc];
    unsigned int cnt = valid ? edeg[tc] : 0u;
    float acc[8];
    #pragma unroll
    for (int c = 0; c < 8; ++c) acc[c] = 0.f;
    for (unsigned int j = 0; j < cnt; j += 4) {    // divergent trip counts ok
        int2 e[4];
        #pragma unroll
        for (int u = 0; u < 4; ++u) {
            unsigned int idx = j + u;
            if (idx >= cnt) idx = cnt - 1;         // cnt>0 inside loop
            e[u] = cs[idx];
        }
        #pragma unroll
        for (int u = 0; u < 4; ++u)
            if (j + u >= cnt) e[u].y = 0;          // alpha := 0 for pad slots
        half8 v[4];
        #pragma unroll
        for (int u = 0; u < 4; ++u)
            v[u] = *((const half8*)(x16 + (size_t)e[u].x * 128) + sl);
        #pragma unroll
        for (int u = 0; u < 4; ++u) {
            float a = __int_as_float(e[u].y);
            #pragma unroll
            for (int c = 0; c < 8; ++c) acc[c] += a * (float)v[u][c];
        }
    }
    float di = dinv[tc];
    float coef = tanhf(al[tc] + ar[tc]) * di * di + FA_EPS;   // self-loop + EPS
    half8 vt = *((const half8*)(x16 + (size_t)tc * 128) + sl);
    #pragma unroll
    for (int c = 0; c < 8; ++c) acc[c] += coef * (float)vt[c];
    if (valid) {
        half8 hv;
        #pragma unroll
        for (int c = 0; c < 8; ++c) hv[c] = (_Float16)acc[c];
        *((half8*)(h16 + (size_t)t * 128) + sl) = hv;
    }
}

// ---------------------------------------------------------------------------
// K7: out = h16 @ W + bias via mfma_f32_16x16x32_f16.
// Block = 4 waves, 64 rows. Wt in LDS, row stride 136 halfs (2-way = free).
// ---------------------------------------------------------------------------
__global__ __launch_bounds__(256) void k_matmul_mfma(
    const _Float16* __restrict__ h16,
    const _Float16* __restrict__ wt,
    const float* __restrict__ bias,
    float* __restrict__ out, int N)
{
    __shared__ _Float16 wl[128 * 136];   // 34 KB
    int tid = threadIdx.x;
    {
        const float* wsrc = (const float*)wt;
        float* wdst = (float*)wl;
        #pragma unroll
        for (int i = tid; i < 8192; i += 256)
            wdst[(i >> 6) * 68 + (i & 63)] = wsrc[i];
    }
    __syncthreads();
    int wv   = tid >> 6;
    int lane = tid & 63;
    int m    = lane & 15;
    int quad = lane >> 4;
    int r0 = (int)blockIdx.x * 64 + wv * 16;
    f32x4 acc[8];
    #pragma unroll
    for (int t = 0; t < 8; ++t) acc[t] = (f32x4)0.f;
    const _Float16* arow = h16 + (size_t)(r0 + m) * 128 + quad * 8;
    #pragma unroll
    for (int k0 = 0; k0 < 128; k0 += 32) {
        half8 a = *(const half8*)(arow + k0);
        #pragma unroll
        for (int t = 0; t < 8; ++t) {
            const _Float16* bp = wl + (size_t)(t * 16 + m) * 136 + quad * 8 + k0;
            half8 b = *(const half8*)bp;
            acc[t] = __builtin_amdgcn_mfma_f32_16x16x32_f16(a, b, acc[t], 0, 0, 0);
        }
    }
    int orow = r0 + quad * 4;
    #pragma unroll
    for (int t = 0; t < 8; ++t) {
        int col = t * 16 + m;
        float bc = bias[col];
        #pragma unroll
        for (int rg = 0; rg < 4; ++rg) {
            int r = orow + rg;
            if (r < N) out[(size_t)r * 128 + col] = acc[t][rg] + bc;
        }
    }
}

extern "C" void kernel_launch(void* const* d_in, const int* in_sizes, int n_in,
                              void* d_out, int out_size, void* d_ws, size_t ws_size,
                              hipStream_t stream)
{
    const float* x     = (const float*)d_in[0];
    const int*   ei    = (const int*)d_in[1];
    const float* att_l = (const float*)d_in[2];
    const float* att_r = (const float*)d_in[3];
    const float* w     = (const float*)d_in[4];
    const float* bias  = (const float*)d_in[5];
    float* out = (float*)d_out;

    const int N  = in_sizes[0] / 128;     // 50000
    const int E  = in_sizes[1] / 2;       // 600000
    const int NB = (N + 255) / 256;       // 196 (<= 256)
    const int NP = ((N + 63) / 64) * 64;  // pad rows for 64-row MFMA tiles

    char* ws = (char*)d_ws;
    _Float16*     h16          = (_Float16*)ws;                         // NP*128
    _Float16*     x16          = h16 + (size_t)NP * 128;                // N*128
    float*        al           = (float*)(x16 + (size_t)N * 128);       // N
    float*        ar           = al + N;
    float*        dinv         = ar + N;
    unsigned int* edeg         = (unsigned int*)(dinv + N);
    unsigned int* offs         = edeg + N;
    unsigned int* cursor       = offs + N;
    unsigned int* partials     = cursor + N;                            // 256
    unsigned int* partial_offs = partials + 256;                        // 256
    int2*         csr          = (int2*)(partial_offs + 256);           // E
    _Float16*     wt           = (_Float16*)(csr + E);                  // 16384

    // K0: al/ar dots, x16 conversion, edeg=0  (2 nodes per wave)
    {
        int waves = (N + 1) / 2;
        k_node_prep<<<(waves * 64 + 255) / 256, 256, 0, stream>>>(
            x, att_l, att_r, al, ar, edeg, x16, N);
    }
    // K1: degree histogram (+ Wt conversion in low blocks)
    k_degree_wconv<<<(E + 255) / 256, 256, 0, stream>>>(ei, edeg, w, wt, E);
    // K2-K4: parallel two-level exclusive scan -> offs/cursor/dinv
    k_reduce<<<NB, 256, 0, stream>>>(edeg, partials, N);
    k_scan_partials<<<1, 256, 0, stream>>>(partials, partial_offs, NB);
    k_chunk_scan<<<NB, 256, 0, stream>>>(edeg, partial_offs, offs, cursor, dinv, N);
    // K5: counting-sort fill
    k_fill<<<(E + 255) / 256, 256, 0, stream>>>(ei, al, ar, dinv, cursor, csr, E);
    // K6: gather (4 nodes per wave, 16B lane loads)
    {
        int waves = (N + 3) / 4;
        k_gather<<<(waves * 64 + 255) / 256, 256, 0, stream>>>(
            x16, csr, offs, edeg, al, ar, dinv, h16, N);
    }
    // K7: matmul + bias
    k_matmul_mfma<<<NP / 64, 256, 0, stream>>>(h16, wt, bias, out, N);
}